// Round 5
// baseline (2874.995 us; speedup 1.0000x reference)
//
#include <hip/hip_runtime.h>

// LSTM B=4096, T=512, D=H=25, 3 layers + MLP head + softmax.
// R5: DS-pipe decongestion. Model: R2-R4 all stuck at ~1.9ms because the
// per-CU LDS pipe (~2.5-3cyc/op, shared by 4 SIMDs) processed ~86 cyc of
// broadcast reads per wave-timestep -> floor 8192*1536*86/256CU = 1.8ms.
// Fix: h-broadcast moves to v_readlane (VALU pipe; each wave redundantly
// updates h so lane j holds h_j), act exchange becomes one b128 read via
// [unit][i,f,g,o] layout, x stays in LDS as 7 b128 broadcasts.
// DS: 33 ops -> 10 ops (~45cyc) per wave-timestep. Weights are NAMED
// scalars (no arrays -> no spill).

#define NT 512
#define ND 25
#define NL 3

__device__ __forceinline__ float exp2f_(float x) { return __builtin_amdgcn_exp2f(x); }
__device__ __forceinline__ float tanhfast(float x) {
    float s = __builtin_amdgcn_rcpf(1.f + exp2f_(-2.885390082f * x));
    return fmaf(2.f, s, -1.f);
}
__device__ __forceinline__ float rdlane(float v, int i) {
    return __uint_as_float(__builtin_amdgcn_readlane(__float_as_uint(v), i));
}

// ---- token lists ----
#define L28(M) M(0) M(1) M(2) M(3) M(4) M(5) M(6) M(7) M(8) M(9) M(10) M(11) \
               M(12) M(13) M(14) M(15) M(16) M(17) M(18) M(19) M(20) M(21) \
               M(22) M(23) M(24) M(25) M(26) M(27)

#define WDECL(i) float wi##i, wh##i;
#define WLOAD(i) wi##i = ((i) < ND) ? wihp[(i) < ND ? (i) : 0] : 0.f; \
                 wh##i = ((i) < ND) ? whhp[(i) < ND ? (i) : 0] : 0.f;

// h-part: 25 terms, 4 rotating chains (readlane -> SGPR-operand FMA)
#define HT(i, A) A = fmaf(wh##i, rdlane(hreg, i), A);

__global__ __launch_bounds__(256, 2)
void lstm5(const float* __restrict__ xin,
           const float* __restrict__ Wih,
           const float* __restrict__ Whh,
           const float* __restrict__ bih,
           const float* __restrict__ bhh,
           const float* __restrict__ W1,
           const float* __restrict__ b1,
           const float* __restrict__ W2,
           const float* __restrict__ b2,
           float* __restrict__ out,
           float* __restrict__ ws)
{
    // x broadcast buffer: [batch-slot][parity][28] (25 + 3 zero pads)
    __shared__ __align__(16) float xb[2][2][28];
    // act exchange: [batch-slot][parity][unit 0..24][i,f,g,o]
    __shared__ __align__(16) float act4[2][2][25][4];

    const int wid  = threadIdx.x >> 6;
    const int lane = threadIdx.x & 63;
    const int wb   = wid >> 1;
    const int role = wid & 1;            // 0: rows 0..49 (i,f)  1: rows 50..99 (g,o)
    const int b    = (blockIdx.x << 1) + wb;

    const int lrow = (lane < 50) ? lane : 49;

    // act4 write slot for this lane
    const int ul   = (lrow >= ND) ? lrow - ND : lrow;       // unit 0..24
    const int slot = role * 2 + (lrow >= ND ? 1 : 0);       // i/f/g/o
    float* const actw0 = &act4[wb][0][ul][slot];
    float* const actw1 = &act4[wb][1][ul][slot];
    const int ur = (lane < ND) ? lane : ND - 1;             // clamped update unit
    const float4* const actr0 = (const float4*)&act4[wb][0][ur][0];
    const float4* const actr1 = (const float4*)&act4[wb][1][ur][0];
    const float4* const xr0 = (const float4*)&xb[wb][0][0];
    const float4* const xr1 = (const float4*)&xb[wb][1][0];
    float* const xw0 = &xb[wb][0][lane < ND ? lane : 0];
    float* const xw1 = &xb[wb][1][lane < ND ? lane : 0];

    // activation constants (hoisted; no divergent branch in loop)
    const bool  isg    = (role == 1) && (lane < ND);
    const float emul   = isg ? -2.885390082f : -1.442695041f;
    const float ascale = isg ?  2.0f : 1.0f;
    const float abias  = isg ? -1.0f : 0.0f;

    L28(WDECL)

    float hreg = 0.f;

    for (int l = 0; l < NL; ++l) {
        const int row = l * 100 + role * 50 + lrow;
        const float* wihp = Wih + row * ND;
        const float* whhp = Whh + row * ND;
        L28(WLOAD)
        const float bias = bih[row] + bhh[row];

        const float* src = (l == 0) ? (xin + (size_t)b * NT * ND)
                                    : (ws  + (size_t)b * NT * ND);
        float* wsrow = ws + (size_t)b * NT * ND;

        __syncthreads();   // prev-layer ws stores drained & visible

        // prime x_0 into parity 0, zero pads in both parities
        if (role == 0) {
            if (lane < ND)       xb[wb][0][lane] = src[lane];
            else if (lane < 28) { xb[wb][0][lane] = 0.f; xb[wb][1][lane] = 0.f; }
        }
        float c = 0.f;
        hreg = 0.f;
        float xnext = (role == 0 && lane < ND) ? src[ND + lane] : 0.f;  // x_1
        __syncthreads();   // priming visible

        for (int t = 0; t < NT; ++t) {
            const int p = t & 1;
            const float4* const xr = p ? xr1 : xr0;

            // ---- x-part: 7 broadcast b128 + 28 FMAs (4 chains) ----
            const float4 v0 = xr[0], v1 = xr[1], v2 = xr[2], v3 = xr[3];
            const float4 v4 = xr[4], v5 = xr[5], v6 = xr[6];
            float a0 = bias, a1 = 0.f, a2 = 0.f, a3 = 0.f;
            a0 = fmaf(wi0,  v0.x, a0); a1 = fmaf(wi1,  v0.y, a1);
            a2 = fmaf(wi2,  v0.z, a2); a3 = fmaf(wi3,  v0.w, a3);
            a0 = fmaf(wi4,  v1.x, a0); a1 = fmaf(wi5,  v1.y, a1);
            a2 = fmaf(wi6,  v1.z, a2); a3 = fmaf(wi7,  v1.w, a3);
            a0 = fmaf(wi8,  v2.x, a0); a1 = fmaf(wi9,  v2.y, a1);
            a2 = fmaf(wi10, v2.z, a2); a3 = fmaf(wi11, v2.w, a3);
            a0 = fmaf(wi12, v3.x, a0); a1 = fmaf(wi13, v3.y, a1);
            a2 = fmaf(wi14, v3.z, a2); a3 = fmaf(wi15, v3.w, a3);
            a0 = fmaf(wi16, v4.x, a0); a1 = fmaf(wi17, v4.y, a1);
            a2 = fmaf(wi18, v4.z, a2); a3 = fmaf(wi19, v4.w, a3);
            a0 = fmaf(wi20, v5.x, a0); a1 = fmaf(wi21, v5.y, a1);
            a2 = fmaf(wi22, v5.z, a2); a3 = fmaf(wi23, v5.w, a3);
            a0 = fmaf(wi24, v6.x, a0); a1 = fmaf(wi25, v6.y, a1);
            a2 = fmaf(wi26, v6.z, a2); a3 = fmaf(wi27, v6.w, a3);

            // ---- h-part: 25 readlane + 25 SGPR-operand FMAs (4 chains) ----
            float b0 = 0.f, b1r = 0.f, b2r = 0.f, b3 = 0.f;
            HT(0,  b0) HT(1,  b1r) HT(2,  b2r) HT(3,  b3)
            HT(4,  b0) HT(5,  b1r) HT(6,  b2r) HT(7,  b3)
            HT(8,  b0) HT(9,  b1r) HT(10, b2r) HT(11, b3)
            HT(12, b0) HT(13, b1r) HT(14, b2r) HT(15, b3)
            HT(16, b0) HT(17, b1r) HT(18, b2r) HT(19, b3)
            HT(20, b0) HT(21, b1r) HT(22, b2r) HT(23, b3)
            HT(24, b0)
            const float acc = ((a0 + a1) + (a2 + a3)) + ((b0 + b1r) + (b2r + b3));

            // ---- activation ----
            const float a = fmaf(ascale,
                                 __builtin_amdgcn_rcpf(1.f + exp2f_(emul * acc)),
                                 abias);
            if (lane < 50) *(p ? actw1 : actw0) = a;

            // ---- stage x_{t+1} into parity p^1 (before the barrier) ----
            if (role == 0 && lane < ND) *(p ? xw0 : xw1) = xnext;
            if (role == 0 && lane < ND && t + 2 < NT)
                xnext = src[(size_t)(t + 2) * ND + lane];

            // LDS-only barrier (no vmcnt drain; globals free-run)
            asm volatile("s_waitcnt lgkmcnt(0)\n\ts_barrier" ::: "memory");

            // ---- redundant update in BOTH waves, all lanes (no divergence) ----
            const float4 q = p ? *actr1 : *actr0;   // (i, f, g, o) activated
            c = fmaf(q.y, c, q.x * q.z);
            hreg = q.w * tanhfast(c);
            if (role == 0 && lane < ND && l < 2) wsrow[(size_t)t * ND + lane] = hreg;
        }
    }

    // ---- head: relu(h W1^T + b1) W2^T + b2, softmax(14) — readlane-only ----
    {
        const int hl = (lane < 16) ? lane : 15;
        float u = b1[hl];
#pragma unroll
        for (int d = 0; d < ND; ++d)
            u = fmaf(W1[hl * ND + d], rdlane(hreg, d), u);
        u = fmaxf(u, 0.f);

        const int cl = (lane < 14) ? lane : 13;
        float lg = b2[cl];
#pragma unroll
        for (int r = 0; r < 16; ++r)
            lg = fmaf(W2[cl * 16 + r], rdlane(u, r), lg);

        float m = -1e30f;
#pragma unroll
        for (int j = 0; j < 14; ++j) m = fmaxf(m, rdlane(lg, j));
        float sum = 0.f;
#pragma unroll
        for (int j = 0; j < 14; ++j)
            sum += exp2f_(1.442695041f * (rdlane(lg, j) - m));
        const float p = exp2f_(1.442695041f * (lg - m)) * __builtin_amdgcn_rcpf(sum);
        if (role == 0 && lane < 14) out[b * 14 + lane] = p;
    }
}

extern "C" void kernel_launch(void* const* d_in, const int* in_sizes, int n_in,
                              void* d_out, int out_size, void* d_ws, size_t ws_size,
                              hipStream_t stream)
{
    const float* x   = (const float*)d_in[0];
    const float* Wih = (const float*)d_in[1];
    const float* Whh = (const float*)d_in[2];
    const float* bih = (const float*)d_in[3];
    const float* bhh = (const float*)d_in[4];
    const float* W1  = (const float*)d_in[5];
    const float* b1  = (const float*)d_in[6];
    const float* W2  = (const float*)d_in[7];
    const float* b2  = (const float*)d_in[8];
    float* outp = (float*)d_out;
    float* ws   = (float*)d_ws;   // 4096*512*25*4 = 209,715,200 bytes

    dim3 grid(4096 / 2), block(256);
    hipLaunchKernelGGL(lstm5, grid, block, 0, stream,
                       x, Wih, Whh, bih, bhh, W1, b1, W2, b2, outp, ws);
}

// Round 6
// 2166.416 us; speedup vs baseline: 1.3271x; 1.3271x over previous
//
#include <hip/hip_runtime.h>

// LSTM B=4096, T=512, D=H=25, 3 layers + MLP head + softmax.
// R6: 2 waves/batch (A: rows 0..49 = i,f ; B: rows 50..99 = g,o), redundant
// cell update in both waves, parity double-buffer, ONE LDS-only barrier/t.
//  - x-part: 7 broadcast ds_read_b128 + 13 v_pk_fma_f32 (R5 had 28 scalar FMA)
//  - h-part: 25 v_readlane + 25 FMA in 4 rotating chains (DS-free broadcast;
//    h_u lives in lane u of every wave thanks to the redundant update)
//  - staging (x prefetch + LDS stage) on wave B, ws store on wave A (balance)
//  - #pragma unroll on the layer loop: weight sets become straight-line live
//    ranges; launch_bounds(256,3) (~170 VGPR cap) -- anti-AGPR-demotion.
// Two-pipe model per CU-timestep: VALU = 8*V, DS = 32*D; V~190cyc, D~35cyc
// -> VALU-bound ~970us if the compiler keeps the 51 weight floats resident.

typedef float f32x2 __attribute__((ext_vector_type(2)));
typedef float f32x4 __attribute__((ext_vector_type(4)));

#define NT 512
#define ND 25

__device__ __forceinline__ float exp2f_(float x) { return __builtin_amdgcn_exp2f(x); }
__device__ __forceinline__ float rcpf_(float x)  { return __builtin_amdgcn_rcpf(x); }
__device__ __forceinline__ float tanhfast(float x) {
    float s = rcpf_(1.f + exp2f_(-2.885390082f * x));
    return fmaf(2.f, s, -1.f);
}
__device__ __forceinline__ float rdlane(float v, int i) {
    return __uint_as_float(__builtin_amdgcn_readlane(__float_as_uint(v), i));
}
__device__ __forceinline__ void pkfma(f32x2& a, f32x2 w, f32x2 v) {
    asm("v_pk_fma_f32 %0, %1, %2, %0" : "+v"(a) : "v"(w), "v"(v));
}
#define LO2(v) __builtin_shufflevector(v, v, 0, 1)
#define HI2(v) __builtin_shufflevector(v, v, 2, 3)

// x-part packed weights wx0..wx12 (wx12 = {w24, 0})
#define WXDECL  f32x2 wx0  = {wihp[0],  wihp[1]},  wx1  = {wihp[2],  wihp[3]},  \
                      wx2  = {wihp[4],  wihp[5]},  wx3  = {wihp[6],  wihp[7]},  \
                      wx4  = {wihp[8],  wihp[9]},  wx5  = {wihp[10], wihp[11]}, \
                      wx6  = {wihp[12], wihp[13]}, wx7  = {wihp[14], wihp[15]}, \
                      wx8  = {wihp[16], wihp[17]}, wx9  = {wihp[18], wihp[19]}, \
                      wx10 = {wihp[20], wihp[21]}, wx11 = {wihp[22], wihp[23]}, \
                      wx12 = {wihp[24], 0.f};
// h-part scalar weights wh0..wh24
#define WHDECL  float wh0  = whhp[0],  wh1  = whhp[1],  wh2  = whhp[2],  \
                      wh3  = whhp[3],  wh4  = whhp[4],  wh5  = whhp[5],  \
                      wh6  = whhp[6],  wh7  = whhp[7],  wh8  = whhp[8],  \
                      wh9  = whhp[9],  wh10 = whhp[10], wh11 = whhp[11], \
                      wh12 = whhp[12], wh13 = whhp[13], wh14 = whhp[14], \
                      wh15 = whhp[15], wh16 = whhp[16], wh17 = whhp[17], \
                      wh18 = whhp[18], wh19 = whhp[19], wh20 = whhp[20], \
                      wh21 = whhp[21], wh22 = whhp[22], wh23 = whhp[23], \
                      wh24 = whhp[24];
#define HT(d, A) A = fmaf(wh##d, rdlane(hreg, d), A);

__global__ __launch_bounds__(256, 3)
void lstm6(const float* __restrict__ xin,
           const float* __restrict__ Wih,
           const float* __restrict__ Whh,
           const float* __restrict__ bih,
           const float* __restrict__ bhh,
           const float* __restrict__ W1,
           const float* __restrict__ b1,
           const float* __restrict__ W2,
           const float* __restrict__ b2,
           float* __restrict__ out,
           float* __restrict__ ws)
{
    __shared__ __align__(16) float xb[2][2][28];        // [slot][parity][x(25)+pad(3)]
    __shared__ __align__(16) float act4[2][2][25][4];   // [slot][parity][unit][i,f,g,o]

    const int wid  = threadIdx.x >> 6;
    const int lane = threadIdx.x & 63;
    const int wb   = wid >> 1;
    const int role = wid & 1;            // 0: rows 0..49 (i,f)  1: rows 50..99 (g,o)
    const int b    = (blockIdx.x << 1) + wb;

    const int lrow = (lane < 50) ? lane : 49;

    const int ul   = (lrow >= ND) ? lrow - ND : lrow;
    const int slot = role * 2 + (lrow >= ND ? 1 : 0);
    float* const actw0 = &act4[wb][0][ul][slot];
    float* const actw1 = &act4[wb][1][ul][slot];
    const int ur = (lane < ND) ? lane : ND - 1;
    const f32x4* const actr0 = (const f32x4*)&act4[wb][0][ur][0];
    const f32x4* const actr1 = (const f32x4*)&act4[wb][1][ur][0];
    const f32x4* const xr0 = (const f32x4*)&xb[wb][0][0];
    const f32x4* const xr1 = (const f32x4*)&xb[wb][1][0];
    float* const xw0 = &xb[wb][0][lane < ND ? lane : 0];
    float* const xw1 = &xb[wb][1][lane < ND ? lane : 0];

    const bool  isg    = (role == 1) && (lane < ND);
    const float emul   = isg ? -2.885390082f : -1.442695041f;
    const float ascale = isg ?  2.0f : 1.0f;
    const float abias  = isg ? -1.0f : 0.0f;

    float hreg = 0.f;

#pragma unroll
    for (int l = 0; l < 3; ++l) {
        const int row = l * 100 + role * 50 + lrow;
        const float* wihp = Wih + row * ND;
        const float* whhp = Whh + row * ND;
        WXDECL
        WHDECL
        const float bias = bih[row] + bhh[row];

        const float* src = (l == 0) ? (xin + (size_t)b * NT * ND)
                                    : (ws  + (size_t)b * NT * ND);
        float* wsrow = ws + (size_t)b * NT * ND;

        __syncthreads();   // prev-layer ws stores drained & visible
        if (role == 1) {   // wave B is the stager
            if (lane < ND)       xb[wb][0][lane] = src[lane];
            else if (lane < 28) { xb[wb][0][lane] = 0.f; xb[wb][1][lane] = 0.f; }
        }
        float c = 0.f;
        hreg = 0.f;
        float xnext = (role == 1 && lane < ND) ? src[ND + lane] : 0.f;  // x_1
        __syncthreads();   // priming visible

        for (int t = 0; t < NT; ++t) {
            const int p = t & 1;
            const f32x4* const xr = p ? xr1 : xr0;

            // ---- x-part: 7 broadcast b128 + 13 v_pk_fma_f32 (4 chains) ----
            const f32x4 v0 = xr[0], v1 = xr[1], v2 = xr[2], v3 = xr[3];
            const f32x4 v4 = xr[4], v5 = xr[5], v6 = xr[6];
            f32x2 A0 = {bias, 0.f}, A1 = {0.f, 0.f}, A2 = {0.f, 0.f}, A3 = {0.f, 0.f};
            pkfma(A0, wx0,  LO2(v0)); pkfma(A1, wx1,  HI2(v0));
            pkfma(A2, wx2,  LO2(v1)); pkfma(A3, wx3,  HI2(v1));
            pkfma(A0, wx4,  LO2(v2)); pkfma(A1, wx5,  HI2(v2));
            pkfma(A2, wx6,  LO2(v3)); pkfma(A3, wx7,  HI2(v3));
            pkfma(A0, wx8,  LO2(v4)); pkfma(A1, wx9,  HI2(v4));
            pkfma(A2, wx10, LO2(v5)); pkfma(A3, wx11, HI2(v5));
            pkfma(A0, wx12, LO2(v6));

            // ---- h-part: 25 readlane + 25 FMA, 4 rotating chains ----
            float b0 = 0.f, b1r = 0.f, b2r = 0.f, b3 = 0.f;
            HT(0,  b0) HT(1,  b1r) HT(2,  b2r) HT(3,  b3)
            HT(4,  b0) HT(5,  b1r) HT(6,  b2r) HT(7,  b3)
            HT(8,  b0) HT(9,  b1r) HT(10, b2r) HT(11, b3)
            HT(12, b0) HT(13, b1r) HT(14, b2r) HT(15, b3)
            HT(16, b0) HT(17, b1r) HT(18, b2r) HT(19, b3)
            HT(20, b0) HT(21, b1r) HT(22, b2r) HT(23, b3)
            HT(24, b0)

            f32x2 S = A0 + A1; S += A2; S += A3;
            const float acc = (S.x + S.y) + ((b0 + b1r) + (b2r + b3));

            // ---- activation ----
            const float a = fmaf(ascale, rcpf_(1.f + exp2f_(emul * acc)), abias);
            if (lane < 50) *(p ? actw1 : actw0) = a;

            // ---- wave B: stage x_{t+1} into parity p^1, prefetch x_{t+2} ----
            if (role == 1 && lane < ND) {
                *(p ? xw0 : xw1) = xnext;
                if (t + 2 < NT) xnext = src[(size_t)(t + 2) * ND + lane];
            }

            // LDS-only barrier (globals free-run; drained at layer boundary)
            asm volatile("s_waitcnt lgkmcnt(0)\n\ts_barrier" ::: "memory");

            // ---- redundant update in BOTH waves ----
            const f32x4 q = p ? *actr1 : *actr0;   // (i, f, g, o)
            c = fmaf(q.y, c, q.x * q.z);
            hreg = q.w * tanhfast(c);
            if (role == 0 && lane < ND && l < 2) wsrow[(size_t)t * ND + lane] = hreg;
        }
    }

    // ---- head: relu(h W1^T + b1) W2^T + b2, softmax(14) — readlane-only ----
    {
        const int hl = (lane < 16) ? lane : 15;
        float u = b1[hl];
#pragma unroll
        for (int d = 0; d < ND; ++d)
            u = fmaf(W1[hl * ND + d], rdlane(hreg, d), u);
        u = fmaxf(u, 0.f);

        const int cl = (lane < 14) ? lane : 13;
        float lg = b2[cl];
#pragma unroll
        for (int r = 0; r < 16; ++r)
            lg = fmaf(W2[cl * 16 + r], rdlane(u, r), lg);

        float m = -1e30f;
#pragma unroll
        for (int j = 0; j < 14; ++j) m = fmaxf(m, rdlane(lg, j));
        float sum = 0.f;
#pragma unroll
        for (int j = 0; j < 14; ++j)
            sum += exp2f_(1.442695041f * (rdlane(lg, j) - m));
        const float p = exp2f_(1.442695041f * (lg - m)) * rcpf_(sum);
        if (role == 0 && lane < 14) out[b * 14 + lane] = p;
    }
}

extern "C" void kernel_launch(void* const* d_in, const int* in_sizes, int n_in,
                              void* d_out, int out_size, void* d_ws, size_t ws_size,
                              hipStream_t stream)
{
    const float* x   = (const float*)d_in[0];
    const float* Wih = (const float*)d_in[1];
    const float* Whh = (const float*)d_in[2];
    const float* bih = (const float*)d_in[3];
    const float* bhh = (const float*)d_in[4];
    const float* W1  = (const float*)d_in[5];
    const float* b1  = (const float*)d_in[6];
    const float* W2  = (const float*)d_in[7];
    const float* b2  = (const float*)d_in[8];
    float* outp = (float*)d_out;
    float* ws   = (float*)d_ws;   // 4096*512*25*4 = 209,715,200 bytes

    dim3 grid(4096 / 2), block(256);
    hipLaunchKernelGGL(lstm6, grid, block, 0, stream,
                       x, Wih, Whh, bih, bhh, W1, b1, W2, b2, outp, ws);
}